// Round 8
// baseline (2548.893 us; speedup 1.0000x reference)
//
#include <hip/hip_runtime.h>

// ---------------------------------------------------------------------------
// LSTMCharacter: two independent LSTMCells (fwd/bwd over same embedded seq),
// B=4096, T=32, H=512, EMB=64, then linear(1024->64)+softmax.
//
// R8 = R5 structure (16x16x32, packW frag order, 64x64 tile, grid 1024,
//      4 blocks/CU) + CORRECT counted-vmcnt pipeline:
//  * BK=32 substeps (16/step), 4 rotating 8KB LDS buffers, depth-2 prefetch
//  * per substep tail: sched_barrier; s_waitcnt vmcnt(2); s_barrier;
//    sched_barrier  -- every wave waits for ITS OWN stage(s+1) loads BEFORE
//    the barrier (8-phase template placement, m195-m201), so the buffer is
//    valid for all waves after the barrier while stage(s+2) stays in flight.
//  * B loads issued before stage(s+2): B-use waits drain only stage(s+1).
// R7's race (wait implicit + after barrier; per-wave vmcnt doesn't cover
// other waves' gll16) fixed; R6's 32x32 repack stays reverted.
// ---------------------------------------------------------------------------

typedef __bf16 bf16x8 __attribute__((ext_vector_type(8)));
typedef float  f32x4  __attribute__((ext_vector_type(4)));

constexpr int BATCH = 4096;
constexpr int TSEQ  = 32;
constexpr int HID   = 512;
constexpr int NG    = 2048;          // 4*HID gate width
constexpr int VOC   = 256;
constexpr int OUTD  = 64;
constexpr int HBUF  = 64 * BATCH * 8;   // 2097152 elems per h buffer (64 k-chunks)

__device__ __forceinline__ unsigned short f2bf(float x) {
  unsigned int u = __builtin_bit_cast(unsigned int, x);
  u += 0x7FFFu + ((u >> 16) & 1u);
  return (unsigned short)(u >> 16);
}
__device__ __forceinline__ float bf2f(unsigned short b) {
  unsigned int u = ((unsigned int)b) << 16;
  return __builtin_bit_cast(float, u);
}
__device__ __forceinline__ float fsig(float x) {
  return __fdividef(1.0f, 1.0f + __expf(-x));
}
__device__ __forceinline__ float ftanh(float x) {
  float e = __expf(-2.0f * fabsf(x));
  float t = (1.0f - e) * __fdividef(1.0f, 1.0f + e);
  return copysignf(t, x);
}
__device__ __forceinline__ bf16x8 ld_frag(const unsigned short* p) {
  uint4 v = *(const uint4*)p;
  return __builtin_bit_cast(bf16x8, v);
}
__device__ __forceinline__ void gll16(const void* g, const void* l) {
  __builtin_amdgcn_global_load_lds(
      (const __attribute__((address_space(1))) unsigned int*)g,
      (__attribute__((address_space(3))) unsigned int*)l, 16, 0, 0);
}

// ---------------------------------------------------------------------------
// G[v][n] = emb[v] . Wih[n] + bih[n] + bhh[n]
// ---------------------------------------------------------------------------
__global__ __launch_bounds__(128)
void build_G(const float* __restrict__ emb, const float* __restrict__ Wih,
             const float* __restrict__ bih, const float* __restrict__ bhh,
             float* __restrict__ G) {
  __shared__ float e[64];
  const int v = blockIdx.y;
  const int tid = threadIdx.x;
  if (tid < 64) e[tid] = emb[v * 64 + tid];
  __syncthreads();
  const int n = blockIdx.x * 128 + tid;
  const float4* w4 = (const float4*)&Wih[n * 64];
  float s = bih[n] + bhh[n];
#pragma unroll
  for (int k = 0; k < 16; ++k) {
    float4 wv = w4[k];
    s += wv.x * e[4 * k] + wv.y * e[4 * k + 1] + wv.z * e[4 * k + 2] + wv.w * e[4 * k + 3];
  }
  G[v * NG + n] = s;
}

// ---------------------------------------------------------------------------
// Pack W[N][K] fp32 into bf16 hi/lo in 16x16 MFMA-fragment order:
// unit p: lane=p&63, c=(p>>6)%nch, f=(p>>6)/nch;
// n = f*16 + (lane&15), k = c*32 + (lane>>4)*8.
// ---------------------------------------------------------------------------
__global__ __launch_bounds__(256)
void packW(const float* __restrict__ W, unsigned short* __restrict__ hi,
           unsigned short* __restrict__ lo, int kdim, int nch, int total) {
  int p = blockIdx.x * 256 + threadIdx.x;
  if (p >= total) return;
  int lane = p & 63;
  int c = (p >> 6) % nch;
  int f = (p >> 6) / nch;
  int n = f * 16 + (lane & 15);
  int k = c * 32 + (lane >> 4) * 8;
  const float* src = &W[(size_t)n * kdim + k];
  unsigned short* dh = &hi[(size_t)p * 8];
  unsigned short* dl = &lo[(size_t)p * 8];
#pragma unroll
  for (int e = 0; e < 8; ++e) {
    float x = src[e];
    unsigned short h = f2bf(x);
    dh[e] = h;
    dl[e] = f2bf(x - bf2f(h));
  }
}

// ---------------------------------------------------------------------------
// One LSTM step for both cells. grid 1024 (XCD-swizzled), block 256 (4 waves).
// Block tile: 64 rows x 64 j-cols (gate tile 64 x 256), K=512, BK=32 substeps.
// Wave w = hs (16-col strip); acc[4 mf][4 gates]; 48 MFMAs per substep.
// Pipeline: 4 x 8KB rotating buffers, stage(s+2) in flight across barriers,
// wait-then-barrier placement (each wave waits vmcnt for its own stages).
// ---------------------------------------------------------------------------
__global__ __launch_bounds__(256, 4)
void lstm_step(const int* __restrict__ xTok,
               const unsigned short* __restrict__ h1r_hi, const unsigned short* __restrict__ h1r_lo,
               unsigned short* __restrict__ h1w_hi, unsigned short* __restrict__ h1w_lo,
               const unsigned short* __restrict__ h2r_hi, const unsigned short* __restrict__ h2r_lo,
               unsigned short* __restrict__ h2w_hi, unsigned short* __restrict__ h2w_lo,
               float* __restrict__ c1, float* __restrict__ c2,
               const unsigned short* __restrict__ W1_hi, const unsigned short* __restrict__ W1_lo,
               const unsigned short* __restrict__ W2_hi, const unsigned short* __restrict__ W2_lo,
               const float* __restrict__ G1, const float* __restrict__ G2,
               int t) {
  const int tid = threadIdx.x;
  const int bid = blockIdx.x;
  const int cell = (bid >> 2) & 1;
  const int j0   = (((bid & 3) << 1) | ((bid >> 9) & 1)) * 64;
  const int m0   = ((bid >> 3) & 63) * 64;

  const unsigned short* hr_hi = cell ? h2r_hi : h1r_hi;
  const unsigned short* hr_lo = cell ? h2r_lo : h1r_lo;
  unsigned short* hw_hi = cell ? h2w_hi : h1w_hi;
  unsigned short* hw_lo = cell ? h2w_lo : h1w_lo;
  float* cbuf = cell ? c2 : c1;
  const unsigned short* Whi = cell ? W2_hi : W1_hi;
  const unsigned short* Wlo = cell ? W2_lo : W1_lo;
  const float* G = cell ? G2 : G1;
  const int tx = cell ? (TSEQ - 1 - t) : t;

  // LDS: 4 rotating sub-buffers: [buf][pol][chunk(4)][row(64)][8] = 8KB each
  __shared__ unsigned short ldsA[4][2][4][64][8];
  __shared__ int toks[64];

  // all 4 waves write the same 64 values (benign duplicate); read in epilogue
  toks[tid & 63] = xTok[(size_t)(m0 + (tid & 63)) * TSEQ + tx];

  const int srow = tid & 63, schk = (tid >> 6) & 3;
  const unsigned short* ghi = hr_hi + (size_t)schk * 32768 + (size_t)(m0 + srow) * 8;
  const unsigned short* glo = hr_lo + (size_t)schk * 32768 + (size_t)(m0 + srow) * 8;
  char* lb0 = ((char*)ldsA) + (tid >> 6) * 1024 + (tid & 63) * 16;

  auto stage = [&](int s) {
    char* lb = lb0 + (s & 3) * 8192;
    const size_t go = (size_t)s * 131072;     // 4 chunks * 32768 elems / substep
    gll16(ghi + go, lb);
    gll16(glo + go, lb + 4096);
  };

  // prologue: stage 0,1 in flight; wait for stage(0) only, then barrier
  stage(0);
  stage(1);
  __builtin_amdgcn_sched_barrier(0);
  asm volatile("s_waitcnt vmcnt(2)" ::: "memory");
  __builtin_amdgcn_s_barrier();
  __builtin_amdgcn_sched_barrier(0);

  const int lane = tid & 63, hs = tid >> 6;
  const int lg = lane >> 4, ll = lane & 15;

  // packed-B per-thread base: frag f = g*32 + fb, fb = j0/16 + hs
  const int fb = (j0 >> 4) + hs;
  const unsigned short* Bh = Whi + ((size_t)(fb * 16) * 64 + lane) * 8;
  const unsigned short* Bl = Wlo + ((size_t)(fb * 16) * 64 + lane) * 8;

  f32x4 acc[4][4] = {};   // [m-frag][gate]

#pragma unroll 1
  for (int s = 0; s < 16; ++s) {
    const int cur = s & 3;
    // B loads first: B-use waits then drain stage(s+1) (older, needed now)
    // but never stage(s+2) (newer).
    bf16x8 bh[4], bl[4];
#pragma unroll
    for (int g = 0; g < 4; ++g) {
      size_t off = (size_t)(g * 512 + s) * 512;
      bh[g] = ld_frag(Bh + off);
      bl[g] = ld_frag(Bl + off);
    }
    __builtin_amdgcn_sched_barrier(0x7);   // only ALU crosses: gll16 stays after B
    if (s < 14) stage(s + 2);
    // A fragments from the ready buffer
    bf16x8 ah[4], al[4];
#pragma unroll
    for (int mf = 0; mf < 4; ++mf) {
      ah[mf] = ld_frag(&ldsA[cur][0][lg][mf * 16 + ll][0]);
      al[mf] = ld_frag(&ldsA[cur][1][lg][mf * 16 + ll][0]);
    }
    __builtin_amdgcn_s_setprio(1);
#pragma unroll
    for (int mf = 0; mf < 4; ++mf) {
#pragma unroll
      for (int g = 0; g < 4; ++g) {
        acc[mf][g] = __builtin_amdgcn_mfma_f32_16x16x32_bf16(ah[mf], bh[g], acc[mf][g], 0, 0, 0);
        acc[mf][g] = __builtin_amdgcn_mfma_f32_16x16x32_bf16(al[mf], bh[g], acc[mf][g], 0, 0, 0);
        acc[mf][g] = __builtin_amdgcn_mfma_f32_16x16x32_bf16(ah[mf], bl[g], acc[mf][g], 0, 0, 0);
      }
    }
    __builtin_amdgcn_s_setprio(0);
    if (s < 15) {
      // wait-THEN-barrier: my own stage(s+1) loads done before the barrier;
      // after the barrier the whole buffer s+1 is valid for every wave.
      __builtin_amdgcn_sched_barrier(0);
      if (s == 14) asm volatile("s_waitcnt vmcnt(0)" ::: "memory");
      else         asm volatile("s_waitcnt vmcnt(2)" ::: "memory");
      __builtin_amdgcn_s_barrier();
      __builtin_amdgcn_sched_barrier(0);
    }
  }

  // ---- fused LSTM cell update (all 4 gates in-register) ----
  const int jcol = j0 + hs * 16 + ll;
#pragma unroll
  for (int mf = 0; mf < 4; ++mf) {
#pragma unroll
    for (int r = 0; r < 4; ++r) {
      int row = mf * 16 + lg * 4 + r;
      int b = m0 + row;
      const float* g4 = &G[(size_t)toks[row] * NG + jcol];
      float pi = acc[mf][0][r] + g4[0];
      float pf = acc[mf][1][r] + g4[512];
      float pg = acc[mf][2][r] + g4[1024];
      float po = acc[mf][3][r] + g4[1536];
      float ig = fsig(pi), fg = fsig(pf), gg = ftanh(pg), og = fsig(po);
      float cold = cbuf[b * HID + jcol];
      float cn = fg * cold + ig * gg;
      cbuf[b * HID + jcol] = cn;
      float hn = og * ftanh(cn);
      unsigned short hh = f2bf(hn);
      unsigned short hl = f2bf(hn - bf2f(hh));
      int hidx = (jcol >> 3) * (BATCH * 8) + b * 8 + (jcol & 7);
      hw_hi[hidx] = hh;
      hw_lo[hidx] = hl;
    }
  }
}

// ---------------------------------------------------------------------------
// out = softmax([h1,h2] @ Wlin.T + blin). grid 64, block 256 (4 waves).
// Wave w: rows m0+w*16..+16, all 64 outputs (4 n-frags), K=1024. WL packed.
// ---------------------------------------------------------------------------
__global__ __launch_bounds__(256)
void final_linsoft(const unsigned short* __restrict__ h1_hi, const unsigned short* __restrict__ h1_lo,
                   const unsigned short* __restrict__ h2_hi, const unsigned short* __restrict__ h2_lo,
                   const unsigned short* __restrict__ WL_hi, const unsigned short* __restrict__ WL_lo,
                   const float* __restrict__ blin, float* __restrict__ out) {
  const int tid = threadIdx.x;
  const int lane = tid & 63;
  const int w = tid >> 6;
  const int lg = lane >> 4, ll = lane & 15;
  const int m0 = blockIdx.x * 64;
  const int arow = m0 + w * 16 + ll;

  f32x4 acc[4] = {};
#pragma unroll 1
  for (int kt = 0; kt < 32; ++kt) {
    const int k0 = kt * 32;
    const unsigned short* ah_ = (k0 < 512) ? h1_hi : h2_hi;
    const unsigned short* al_ = (k0 < 512) ? h1_lo : h2_lo;
    const int kk0 = k0 & 511;
    const int aidx = (kk0 / 8 + lg) * (BATCH * 8) + arow * 8;
    bf16x8 ah = ld_frag(&ah_[aidx]);
    bf16x8 al = ld_frag(&al_[aidx]);
#pragma unroll
    for (int nf = 0; nf < 4; ++nf) {
      size_t boff = (((size_t)nf * 32 + kt) * 64 + lane) * 8;
      bf16x8 bh = ld_frag(&WL_hi[boff]);
      bf16x8 bl = ld_frag(&WL_lo[boff]);
      acc[nf] = __builtin_amdgcn_mfma_f32_16x16x32_bf16(ah, bh, acc[nf], 0, 0, 0);
      acc[nf] = __builtin_amdgcn_mfma_f32_16x16x32_bf16(al, bh, acc[nf], 0, 0, 0);
      acc[nf] = __builtin_amdgcn_mfma_f32_16x16x32_bf16(ah, bl, acc[nf], 0, 0, 0);
    }
  }

  float bl4[4];
#pragma unroll
  for (int nf = 0; nf < 4; ++nf) bl4[nf] = blin[nf * 16 + ll];

#pragma unroll
  for (int r = 0; r < 4; ++r) {
    float z[4];
    float mx = -3.4e38f;
#pragma unroll
    for (int nf = 0; nf < 4; ++nf) { z[nf] = acc[nf][r] + bl4[nf]; mx = fmaxf(mx, z[nf]); }
#pragma unroll
    for (int d = 1; d < 16; d <<= 1) mx = fmaxf(mx, __shfl_xor(mx, d));
    float s = 0.f;
#pragma unroll
    for (int nf = 0; nf < 4; ++nf) { z[nf] = __expf(z[nf] - mx); s += z[nf]; }
#pragma unroll
    for (int d = 1; d < 16; d <<= 1) s += __shfl_xor(s, d);
    float inv = __fdividef(1.0f, s);
    int row = m0 + w * 16 + lg * 4 + r;
#pragma unroll
    for (int nf = 0; nf < 4; ++nf) out[row * OUTD + nf * 16 + ll] = z[nf] * inv;
  }
}

// ---------------------------------------------------------------------------
extern "C" void kernel_launch(void* const* d_in, const int* in_sizes, int n_in,
                              void* d_out, int out_size, void* d_ws, size_t ws_size,
                              hipStream_t stream) {
  const int*   x    = (const int*)  d_in[0];
  // d_in[1] = mask: unused by reference
  const float* emb  = (const float*)d_in[2];
  const float* Wih1 = (const float*)d_in[3];
  const float* Whh1 = (const float*)d_in[4];
  const float* bih1 = (const float*)d_in[5];
  const float* bhh1 = (const float*)d_in[6];
  const float* Wih2 = (const float*)d_in[7];
  const float* Whh2 = (const float*)d_in[8];
  const float* bih2 = (const float*)d_in[9];
  const float* bhh2 = (const float*)d_in[10];
  const float* Wlin = (const float*)d_in[11];
  const float* blin = (const float*)d_in[12];
  float* out = (float*)d_out;

  char* p = (char*)d_ws;
  auto alloc = [&](size_t b) { char* r = p; p += (b + 255) & ~(size_t)255; return r; };

  float* G1 = (float*)alloc((size_t)VOC * NG * 4);
  float* G2 = (float*)alloc((size_t)VOC * NG * 4);
  unsigned short* W1_hi = (unsigned short*)alloc((size_t)NG * HID * 2);
  unsigned short* W1_lo = (unsigned short*)alloc((size_t)NG * HID * 2);
  unsigned short* W2_hi = (unsigned short*)alloc((size_t)NG * HID * 2);
  unsigned short* W2_lo = (unsigned short*)alloc((size_t)NG * HID * 2);
  unsigned short* WL_hi = (unsigned short*)alloc((size_t)OUTD * 1024 * 2);
  unsigned short* WL_lo = (unsigned short*)alloc((size_t)OUTD * 1024 * 2);
  unsigned short* h1_hi = (unsigned short*)alloc((size_t)2 * HBUF * 2);
  unsigned short* h1_lo = (unsigned short*)alloc((size_t)2 * HBUF * 2);
  unsigned short* h2_hi = (unsigned short*)alloc((size_t)2 * HBUF * 2);
  unsigned short* h2_lo = (unsigned short*)alloc((size_t)2 * HBUF * 2);
  float* c1 = (float*)alloc((size_t)BATCH * HID * 4);
  float* c2 = (float*)alloc((size_t)BATCH * HID * 4);

  if ((size_t)(p - (char*)d_ws) > ws_size) return;

  hipMemsetAsync(h1_hi, 0, (size_t)HBUF * 2, stream);
  hipMemsetAsync(h1_lo, 0, (size_t)HBUF * 2, stream);
  hipMemsetAsync(h2_hi, 0, (size_t)HBUF * 2, stream);
  hipMemsetAsync(h2_lo, 0, (size_t)HBUF * 2, stream);
  hipMemsetAsync(c1, 0, (size_t)BATCH * HID * 4, stream);
  hipMemsetAsync(c2, 0, (size_t)BATCH * HID * 4, stream);

  // weight preprocessing: pack to 16x16 MFMA-fragment order, bf16 hi/lo
  packW<<<dim3(512), 256, 0, stream>>>(Whh1, W1_hi, W1_lo, HID, 16, NG * HID / 8);
  packW<<<dim3(512), 256, 0, stream>>>(Whh2, W2_hi, W2_lo, HID, 16, NG * HID / 8);
  packW<<<dim3(32), 256, 0, stream>>>(Wlin, WL_hi, WL_lo, 1024, 32, OUTD * 1024 / 8);
  build_G<<<dim3(16, VOC), 128, 0, stream>>>(emb, Wih1, bih1, bhh1, G1);
  build_G<<<dim3(16, VOC), 128, 0, stream>>>(emb, Wih2, bih2, bhh2, G2);

  // 32 recurrent steps, both cells per launch; ping-pong h buffers
  for (int t = 0; t < TSEQ; ++t) {
    int rb = t & 1, wb = rb ^ 1;
    lstm_step<<<dim3(1024), 256, 0, stream>>>(x,
        h1_hi + (size_t)rb * HBUF, h1_lo + (size_t)rb * HBUF,
        h1_hi + (size_t)wb * HBUF, h1_lo + (size_t)wb * HBUF,
        h2_hi + (size_t)rb * HBUF, h2_lo + (size_t)rb * HBUF,
        h2_hi + (size_t)wb * HBUF, h2_lo + (size_t)wb * HBUF,
        c1, c2, W1_hi, W1_lo, W2_hi, W2_lo, G1, G2, t);
  }
  // after t=31 (odd), final h lives in buffer 0
  final_linsoft<<<dim3(64), 256, 0, stream>>>(h1_hi, h1_lo, h2_hi, h2_lo,
                                              WL_hi, WL_lo, blin, out);
}

// Round 9
// 1953.656 us; speedup vs baseline: 1.3047x; 1.3047x over previous
//
#include <hip/hip_runtime.h>

// ---------------------------------------------------------------------------
// LSTMCharacter: two independent LSTMCells (fwd/bwd over same embedded seq),
// B=4096, T=32, H=512, EMB=64, then linear(1024->64)+softmax.
//
// R9 = R5 structure exactly (16x16x32, packW frag order, 64x64 tile,
//      grid 1024, BK=64 kt-loop, plain __syncthreads) with two changes:
//  * __launch_bounds__(256,3): 170-reg budget (was 128 at ,4). R5/R7/R8 all
//    compiled to VGPR_Count=64 (+64 AGPR acc = the full 128): operand loads
//    were register-starved and serialized, exposing L2 latency per phase.
//    ~140 regs lets the compiler hoist all 8 B-frags + 8 A-frags.
//  * per-block K-phase rotation (start=f(bid)&7): co-resident blocks walk
//    k-chunks in different order -> memory phases de-convoy. FP-order change
//    only (3.3x absmax headroom).
// R6 (32x32 repack: FETCH x3.4) and R7/R8 (substep pipeline: 83us) reverted.
// ---------------------------------------------------------------------------

typedef __bf16 bf16x8 __attribute__((ext_vector_type(8)));
typedef float  f32x4  __attribute__((ext_vector_type(4)));

constexpr int BATCH = 4096;
constexpr int TSEQ  = 32;
constexpr int HID   = 512;
constexpr int NG    = 2048;          // 4*HID gate width
constexpr int VOC   = 256;
constexpr int OUTD  = 64;
constexpr int HBUF  = 64 * BATCH * 8;   // 2097152 elems per h buffer (64 k-chunks)

__device__ __forceinline__ unsigned short f2bf(float x) {
  unsigned int u = __builtin_bit_cast(unsigned int, x);
  u += 0x7FFFu + ((u >> 16) & 1u);
  return (unsigned short)(u >> 16);
}
__device__ __forceinline__ float bf2f(unsigned short b) {
  unsigned int u = ((unsigned int)b) << 16;
  return __builtin_bit_cast(float, u);
}
__device__ __forceinline__ float fsig(float x) {
  return __fdividef(1.0f, 1.0f + __expf(-x));
}
__device__ __forceinline__ float ftanh(float x) {
  float e = __expf(-2.0f * fabsf(x));
  float t = (1.0f - e) * __fdividef(1.0f, 1.0f + e);
  return copysignf(t, x);
}
__device__ __forceinline__ bf16x8 ld_frag(const unsigned short* p) {
  uint4 v = *(const uint4*)p;
  return __builtin_bit_cast(bf16x8, v);
}
__device__ __forceinline__ void gll16(const void* g, const void* l) {
  __builtin_amdgcn_global_load_lds(
      (const __attribute__((address_space(1))) unsigned int*)g,
      (__attribute__((address_space(3))) unsigned int*)l, 16, 0, 0);
}

// ---------------------------------------------------------------------------
// G[v][n] = emb[v] . Wih[n] + bih[n] + bhh[n]
// ---------------------------------------------------------------------------
__global__ __launch_bounds__(128)
void build_G(const float* __restrict__ emb, const float* __restrict__ Wih,
             const float* __restrict__ bih, const float* __restrict__ bhh,
             float* __restrict__ G) {
  __shared__ float e[64];
  const int v = blockIdx.y;
  const int tid = threadIdx.x;
  if (tid < 64) e[tid] = emb[v * 64 + tid];
  __syncthreads();
  const int n = blockIdx.x * 128 + tid;
  const float4* w4 = (const float4*)&Wih[n * 64];
  float s = bih[n] + bhh[n];
#pragma unroll
  for (int k = 0; k < 16; ++k) {
    float4 wv = w4[k];
    s += wv.x * e[4 * k] + wv.y * e[4 * k + 1] + wv.z * e[4 * k + 2] + wv.w * e[4 * k + 3];
  }
  G[v * NG + n] = s;
}

// ---------------------------------------------------------------------------
// Pack W[N][K] fp32 into bf16 hi/lo in 16x16 MFMA-fragment order:
// unit p: lane=p&63, c=(p>>6)%nch, f=(p>>6)/nch;
// n = f*16 + (lane&15), k = c*32 + (lane>>4)*8.
// ---------------------------------------------------------------------------
__global__ __launch_bounds__(256)
void packW(const float* __restrict__ W, unsigned short* __restrict__ hi,
           unsigned short* __restrict__ lo, int kdim, int nch, int total) {
  int p = blockIdx.x * 256 + threadIdx.x;
  if (p >= total) return;
  int lane = p & 63;
  int c = (p >> 6) % nch;
  int f = (p >> 6) / nch;
  int n = f * 16 + (lane & 15);
  int k = c * 32 + (lane >> 4) * 8;
  const float* src = &W[(size_t)n * kdim + k];
  unsigned short* dh = &hi[(size_t)p * 8];
  unsigned short* dl = &lo[(size_t)p * 8];
#pragma unroll
  for (int e = 0; e < 8; ++e) {
    float x = src[e];
    unsigned short h = f2bf(x);
    dh[e] = h;
    dl[e] = f2bf(x - bf2f(h));
  }
}

// ---------------------------------------------------------------------------
// One LSTM step for both cells. grid 1024 (XCD-swizzled), block 256 (4 waves).
// Block tile: 64 rows x 64 j-cols (gate tile 64 x 256), K=512, BK=64.
// Wave w = hs (16-col strip); acc[4 mf][4 gates]; 96 MFMAs per kt.
// K-chunks processed in per-block rotated order (de-convoy).
// ---------------------------------------------------------------------------
__global__ __launch_bounds__(256, 3)
void lstm_step(const int* __restrict__ xTok,
               const unsigned short* __restrict__ h1r_hi, const unsigned short* __restrict__ h1r_lo,
               unsigned short* __restrict__ h1w_hi, unsigned short* __restrict__ h1w_lo,
               const unsigned short* __restrict__ h2r_hi, const unsigned short* __restrict__ h2r_lo,
               unsigned short* __restrict__ h2w_hi, unsigned short* __restrict__ h2w_lo,
               float* __restrict__ c1, float* __restrict__ c2,
               const unsigned short* __restrict__ W1_hi, const unsigned short* __restrict__ W1_lo,
               const unsigned short* __restrict__ W2_hi, const unsigned short* __restrict__ W2_lo,
               const float* __restrict__ G1, const float* __restrict__ G2,
               int t) {
  const int tid = threadIdx.x;
  const int bid = blockIdx.x;
  const int cell = (bid >> 2) & 1;
  const int j0   = (((bid & 3) << 1) | ((bid >> 9) & 1)) * 64;
  const int m0   = ((bid >> 3) & 63) * 64;
  const int start = (bid ^ (bid >> 3) ^ (bid >> 6) ^ (bid >> 9)) & 7;

  const unsigned short* hr_hi = cell ? h2r_hi : h1r_hi;
  const unsigned short* hr_lo = cell ? h2r_lo : h1r_lo;
  unsigned short* hw_hi = cell ? h2w_hi : h1w_hi;
  unsigned short* hw_lo = cell ? h2w_lo : h1w_lo;
  float* cbuf = cell ? c2 : c1;
  const unsigned short* Whi = cell ? W2_hi : W1_hi;
  const unsigned short* Wlo = cell ? W2_lo : W1_lo;
  const float* G = cell ? G2 : G1;
  const int tx = cell ? (TSEQ - 1 - t) : t;

  // LDS: [buf][pol][chunk(8)][row(64)][8] bf16 = 32 KB
  __shared__ unsigned short ldsA[2][2][8][64][8];
  __shared__ int toks[64];
  if (tid < 64) toks[tid] = xTok[(size_t)(m0 + tid) * TSEQ + tx];

  const int srow = tid & 63, schk = tid >> 6;   // chunk 0..3, row 0..63
  const unsigned short* ghi = hr_hi + (size_t)schk * 32768 + (size_t)(m0 + srow) * 8;
  const unsigned short* glo = hr_lo + (size_t)schk * 32768 + (size_t)(m0 + srow) * 8;
  char* lbase = ((char*)ldsA) + tid * 16;

  auto stage = [&](int p, int buf) {
    const size_t go = (size_t)p * (8 * 32768);
    char* lb = lbase + buf * 16384;
    gll16(ghi + go,             lb);
    gll16(ghi + go + 4 * 32768, lb + 4096);
    gll16(glo + go,             lb + 8192);
    gll16(glo + go + 4 * 32768, lb + 12288);
  };

  stage(start, 0);
  __syncthreads();

  const int lane = tid & 63, hs = tid >> 6;
  const int lg = lane >> 4, ll = lane & 15;

  // packed-B per-thread base: frag f = g*32 + fb, fb = j0/16 + hs
  const int fb = (j0 >> 4) + hs;
  const unsigned short* Bh = Whi + ((size_t)(fb * 16) * 64 + lane) * 8;
  const unsigned short* Bl = Wlo + ((size_t)(fb * 16) * 64 + lane) * 8;

  f32x4 acc[4][4] = {};   // [m-frag][gate]

#pragma unroll 1
  for (int i = 0; i < 8; ++i) {
    const int p = (i + start) & 7;      // rotated k-chunk index
    const int cur = i & 1;
    if (i < 7) stage((p + 1) & 7, cur ^ 1);
#pragma unroll
    for (int h = 0; h < 2; ++h) {
      const int c = p * 2 + h;
      bf16x8 bh[4], bl[4];
#pragma unroll
      for (int g = 0; g < 4; ++g) {
        size_t off = ((size_t)(g * 512 + c)) * 512;
        bh[g] = ld_frag(Bh + off);
        bl[g] = ld_frag(Bl + off);
      }
#pragma unroll
      for (int mf = 0; mf < 4; ++mf) {
        const int row = mf * 16 + ll;
        bf16x8 ah = ld_frag(&ldsA[cur][0][h * 4 + lg][row][0]);
        bf16x8 al = ld_frag(&ldsA[cur][1][h * 4 + lg][row][0]);
#pragma unroll
        for (int g = 0; g < 4; ++g) {
          acc[mf][g] = __builtin_amdgcn_mfma_f32_16x16x32_bf16(ah, bh[g], acc[mf][g], 0, 0, 0);
          acc[mf][g] = __builtin_amdgcn_mfma_f32_16x16x32_bf16(al, bh[g], acc[mf][g], 0, 0, 0);
          acc[mf][g] = __builtin_amdgcn_mfma_f32_16x16x32_bf16(ah, bl[g], acc[mf][g], 0, 0, 0);
        }
      }
    }
    __syncthreads();
  }

  // ---- fused LSTM cell update (all 4 gates in-register) ----
  const int jcol = j0 + hs * 16 + ll;
#pragma unroll
  for (int mf = 0; mf < 4; ++mf) {
#pragma unroll
    for (int r = 0; r < 4; ++r) {
      int row = mf * 16 + lg * 4 + r;
      int b = m0 + row;
      const float* g4 = &G[(size_t)toks[row] * NG + jcol];
      float pi = acc[mf][0][r] + g4[0];
      float pf = acc[mf][1][r] + g4[512];
      float pg = acc[mf][2][r] + g4[1024];
      float po = acc[mf][3][r] + g4[1536];
      float ig = fsig(pi), fg = fsig(pf), gg = ftanh(pg), og = fsig(po);
      float cold = cbuf[b * HID + jcol];
      float cn = fg * cold + ig * gg;
      cbuf[b * HID + jcol] = cn;
      float hn = og * ftanh(cn);
      unsigned short hh = f2bf(hn);
      unsigned short hl = f2bf(hn - bf2f(hh));
      int hidx = (jcol >> 3) * (BATCH * 8) + b * 8 + (jcol & 7);
      hw_hi[hidx] = hh;
      hw_lo[hidx] = hl;
    }
  }
}

// ---------------------------------------------------------------------------
// out = softmax([h1,h2] @ Wlin.T + blin). grid 64, block 256 (4 waves).
// Wave w: rows m0+w*16..+16, all 64 outputs (4 n-frags), K=1024. WL packed.
// ---------------------------------------------------------------------------
__global__ __launch_bounds__(256)
void final_linsoft(const unsigned short* __restrict__ h1_hi, const unsigned short* __restrict__ h1_lo,
                   const unsigned short* __restrict__ h2_hi, const unsigned short* __restrict__ h2_lo,
                   const unsigned short* __restrict__ WL_hi, const unsigned short* __restrict__ WL_lo,
                   const float* __restrict__ blin, float* __restrict__ out) {
  const int tid = threadIdx.x;
  const int lane = tid & 63;
  const int w = tid >> 6;
  const int lg = lane >> 4, ll = lane & 15;
  const int m0 = blockIdx.x * 64;
  const int arow = m0 + w * 16 + ll;

  f32x4 acc[4] = {};
#pragma unroll 1
  for (int kt = 0; kt < 32; ++kt) {
    const int k0 = kt * 32;
    const unsigned short* ah_ = (k0 < 512) ? h1_hi : h2_hi;
    const unsigned short* al_ = (k0 < 512) ? h1_lo : h2_lo;
    const int kk0 = k0 & 511;
    const int aidx = (kk0 / 8 + lg) * (BATCH * 8) + arow * 8;
    bf16x8 ah = ld_frag(&ah_[aidx]);
    bf16x8 al = ld_frag(&al_[aidx]);
#pragma unroll
    for (int nf = 0; nf < 4; ++nf) {
      size_t boff = (((size_t)nf * 32 + kt) * 64 + lane) * 8;
      bf16x8 bh = ld_frag(&WL_hi[boff]);
      bf16x8 bl = ld_frag(&WL_lo[boff]);
      acc[nf] = __builtin_amdgcn_mfma_f32_16x16x32_bf16(ah, bh, acc[nf], 0, 0, 0);
      acc[nf] = __builtin_amdgcn_mfma_f32_16x16x32_bf16(al, bh, acc[nf], 0, 0, 0);
      acc[nf] = __builtin_amdgcn_mfma_f32_16x16x32_bf16(ah, bl, acc[nf], 0, 0, 0);
    }
  }

  float bl4[4];
#pragma unroll
  for (int nf = 0; nf < 4; ++nf) bl4[nf] = blin[nf * 16 + ll];

#pragma unroll
  for (int r = 0; r < 4; ++r) {
    float z[4];
    float mx = -3.4e38f;
#pragma unroll
    for (int nf = 0; nf < 4; ++nf) { z[nf] = acc[nf][r] + bl4[nf]; mx = fmaxf(mx, z[nf]); }
#pragma unroll
    for (int d = 1; d < 16; d <<= 1) mx = fmaxf(mx, __shfl_xor(mx, d));
    float s = 0.f;
#pragma unroll
    for (int nf = 0; nf < 4; ++nf) { z[nf] = __expf(z[nf] - mx); s += z[nf]; }
#pragma unroll
    for (int d = 1; d < 16; d <<= 1) s += __shfl_xor(s, d);
    float inv = __fdividef(1.0f, s);
    int row = m0 + w * 16 + lg * 4 + r;
#pragma unroll
    for (int nf = 0; nf < 4; ++nf) out[row * OUTD + nf * 16 + ll] = z[nf] * inv;
  }
}

// ---------------------------------------------------------------------------
extern "C" void kernel_launch(void* const* d_in, const int* in_sizes, int n_in,
                              void* d_out, int out_size, void* d_ws, size_t ws_size,
                              hipStream_t stream) {
  const int*   x    = (const int*)  d_in[0];
  // d_in[1] = mask: unused by reference
  const float* emb  = (const float*)d_in[2];
  const float* Wih1 = (const float*)d_in[3];
  const float* Whh1 = (const float*)d_in[4];
  const float* bih1 = (const float*)d_in[5];
  const float* bhh1 = (const float*)d_in[6];
  const float* Wih2 = (const float*)d_in[7];
  const float* Whh2 = (const float*)d_in[8];
  const float* bih2 = (const float*)d_in[9];
  const float* bhh2 = (const float*)d_in[10];
  const float* Wlin = (const float*)d_in[11];
  const float* blin = (const float*)d_in[12];
  float* out = (float*)d_out;

  char* p = (char*)d_ws;
  auto alloc = [&](size_t b) { char* r = p; p += (b + 255) & ~(size_t)255; return r; };

  float* G1 = (float*)alloc((size_t)VOC * NG * 4);
  float* G2 = (float*)alloc((size_t)VOC * NG * 4);
  unsigned short* W1_hi = (unsigned short*)alloc((size_t)NG * HID * 2);
  unsigned short* W1_lo = (unsigned short*)alloc((size_t)NG * HID * 2);
  unsigned short* W2_hi = (unsigned short*)alloc((size_t)NG * HID * 2);
  unsigned short* W2_lo = (unsigned short*)alloc((size_t)NG * HID * 2);
  unsigned short* WL_hi = (unsigned short*)alloc((size_t)OUTD * 1024 * 2);
  unsigned short* WL_lo = (unsigned short*)alloc((size_t)OUTD * 1024 * 2);
  unsigned short* h1_hi = (unsigned short*)alloc((size_t)2 * HBUF * 2);
  unsigned short* h1_lo = (unsigned short*)alloc((size_t)2 * HBUF * 2);
  unsigned short* h2_hi = (unsigned short*)alloc((size_t)2 * HBUF * 2);
  unsigned short* h2_lo = (unsigned short*)alloc((size_t)2 * HBUF * 2);
  float* c1 = (float*)alloc((size_t)BATCH * HID * 4);
  float* c2 = (float*)alloc((size_t)BATCH * HID * 4);

  if ((size_t)(p - (char*)d_ws) > ws_size) return;

  hipMemsetAsync(h1_hi, 0, (size_t)HBUF * 2, stream);
  hipMemsetAsync(h1_lo, 0, (size_t)HBUF * 2, stream);
  hipMemsetAsync(h2_hi, 0, (size_t)HBUF * 2, stream);
  hipMemsetAsync(h2_lo, 0, (size_t)HBUF * 2, stream);
  hipMemsetAsync(c1, 0, (size_t)BATCH * HID * 4, stream);
  hipMemsetAsync(c2, 0, (size_t)BATCH * HID * 4, stream);

  // weight preprocessing: pack to 16x16 MFMA-fragment order, bf16 hi/lo
  packW<<<dim3(512), 256, 0, stream>>>(Whh1, W1_hi, W1_lo, HID, 16, NG * HID / 8);
  packW<<<dim3(512), 256, 0, stream>>>(Whh2, W2_hi, W2_lo, HID, 16, NG * HID / 8);
  packW<<<dim3(32), 256, 0, stream>>>(Wlin, WL_hi, WL_lo, 1024, 32, OUTD * 1024 / 8);
  build_G<<<dim3(16, VOC), 128, 0, stream>>>(emb, Wih1, bih1, bhh1, G1);
  build_G<<<dim3(16, VOC), 128, 0, stream>>>(emb, Wih2, bih2, bhh2, G2);

  // 32 recurrent steps, both cells per launch; ping-pong h buffers
  for (int t = 0; t < TSEQ; ++t) {
    int rb = t & 1, wb = rb ^ 1;
    lstm_step<<<dim3(1024), 256, 0, stream>>>(x,
        h1_hi + (size_t)rb * HBUF, h1_lo + (size_t)rb * HBUF,
        h1_hi + (size_t)wb * HBUF, h1_lo + (size_t)wb * HBUF,
        h2_hi + (size_t)rb * HBUF, h2_lo + (size_t)rb * HBUF,
        h2_hi + (size_t)wb * HBUF, h2_lo + (size_t)wb * HBUF,
        c1, c2, W1_hi, W1_lo, W2_hi, W2_lo, G1, G2, t);
  }
  // after t=31 (odd), final h lives in buffer 0
  final_linsoft<<<dim3(64), 256, 0, stream>>>(h1_hi, h1_lo, h2_hi, h2_lo,
                                              WL_hi, WL_lo, blin, out);
}